// Round 20
// baseline (2882.397 us; speedup 1.0000x reference)
//
#include <hip/hip_runtime.h>
#include <stdint.h>

// ---------- types ----------
typedef short short8v __attribute__((ext_vector_type(8)));
typedef unsigned short u16x8 __attribute__((ext_vector_type(8)));
typedef float f32x4  __attribute__((ext_vector_type(4)));
typedef unsigned long long u64;

__device__ inline uint16_t f2bf(float f){
  uint32_t u = __float_as_uint(f);
  uint32_t r = (u + 0x7fffu + ((u >> 16) & 1u)) >> 16;
  return (uint16_t)r;
}
__device__ inline float bf2f(uint16_t h){
  return __uint_as_float(((uint32_t)h) << 16);
}

// ---------- f32 -> bf16 conversion (vectorized) ----------
__global__ void cvt_f32_bf16(const float* __restrict__ src, uint16_t* __restrict__ dst, int n4){
  int i = blockIdx.x * blockDim.x + threadIdx.x;
  int stride = gridDim.x * blockDim.x;
  for (; i < n4; i += stride){
    float4 v = ((const float4*)src)[i];
    uint64_t p = (uint64_t)f2bf(v.x)
               | ((uint64_t)f2bf(v.y) << 16)
               | ((uint64_t)f2bf(v.z) << 32)
               | ((uint64_t)f2bf(v.w) << 48);
    ((uint64_t*)dst)[i] = p;
  }
}

// ---------- bf16 GEMM: C[m,n] = sum_k A[m,k] * Bw[n,k] + bias[n]  (C bf16) ----------
#define GL2LDS(g, l) __builtin_amdgcn_global_load_lds((const __attribute__((address_space(1))) unsigned int*)(g), (__attribute__((address_space(3))) unsigned int*)(l), 16, 0, 0)

__global__ __launch_bounds__(256) void gemm_bt_bias(
    const uint16_t* __restrict__ A, const uint16_t* __restrict__ Bw,
    const float* __restrict__ bias, uint16_t* __restrict__ C,
    int M, int N, int K)
{
  __shared__ uint16_t As[128 * 64];
  __shared__ uint16_t Bs[128 * 64];
  const int tid  = threadIdx.x;
  const int lane = tid & 63, wid = tid >> 6;
  const int n0 = blockIdx.x * 128, m0 = blockIdx.y * 128;
  const int wrow = (wid & 1) * 64, wcol = (wid >> 1) * 64;
  const int l15 = lane & 15, l4 = lane >> 4;
  const int srow = lane >> 3, scol = (lane & 7) * 8;
  const size_t Ks = (size_t)K;

  f32x4 acc[4][4] = {};

  for (int kt = 0; kt < K; kt += 64){
    __syncthreads();
    const uint16_t* gA = A  + (size_t)m0 * Ks + kt;
    const uint16_t* gB = Bw + (size_t)n0 * Ks + kt;
    #pragma unroll
    for (int i = 0; i < 4; ++i){
      int rb = wid * 32 + i * 8;
      GL2LDS(gA + (size_t)(rb + srow) * Ks + scol, &As[rb * 64]);
      GL2LDS(gB + (size_t)(rb + srow) * Ks + scol, &Bs[rb * 64]);
    }
    __syncthreads();
    #pragma unroll
    for (int kk = 0; kk < 2; ++kk){
      short8v a[4], b[4];
      int koff = kk * 32 + l4 * 8;
      #pragma unroll
      for (int mt = 0; mt < 4; ++mt) a[mt] = *(const short8v*)&As[(wrow + mt*16 + l15) * 64 + koff];
      #pragma unroll
      for (int nt = 0; nt < 4; ++nt) b[nt] = *(const short8v*)&Bs[(wcol + nt*16 + l15) * 64 + koff];
      #pragma unroll
      for (int mt = 0; mt < 4; ++mt)
        #pragma unroll
        for (int nt = 0; nt < 4; ++nt)
          acc[mt][nt] = __builtin_amdgcn_mfma_f32_16x16x32_bf16(a[mt], b[nt], acc[mt][nt], 0, 0, 0);
    }
  }
  #pragma unroll
  for (int mt = 0; mt < 4; ++mt)
    #pragma unroll
    for (int nt = 0; nt < 4; ++nt){
      int col = n0 + wcol + nt * 16 + l15;
      float bv = bias[col];
      int rbase = m0 + wrow + mt * 16 + l4 * 4;
      #pragma unroll
      for (int j = 0; j < 4; ++j)
        C[(size_t)(rbase + j) * (size_t)N + col] = f2bf(acc[mt][nt][j] + bv);
    }
}

// LDS reduce index: 8 waves x 96 (3 gates x 32 cols) x 16 rows, stride 20 f32.
// f32x4 writes: granule = (c*5 + (m/4 ^ (c&3))) mod 8 — 16 c cover residues
// evenly, XOR spreads intra-granule -> 2-way max (free). Reads <=4-way (minor).
__device__ inline int ridx(int w, int c, int m){
  return (w * 96 + c) * 20 + (m ^ ((c & 3) << 2));
}

// 16B MALL-direct load (bypass L1+L2) — proven r4/r10
#define HLOAD(dst, addr) \
  asm volatile("global_load_dwordx4 %0, %1, off sc0 sc1" : "=v"(dst) : "v"(addr) : "memory")
// plain cached 2B load (xp)
#define XPLOAD2(dst, addr) \
  asm volatile("global_load_ushort %0, %1, off" : "=v"(dst) : "v"(addr) : "memory")
// write-through 2B store (h / sentinel), fire-and-forget
#define HSTORE2(addr, val) \
  asm volatile("global_store_short %0, %1, off sc0 sc1" :: "v"(addr), "v"(val) : "memory")
#define OSTORE2(addr, val) \
  asm volatile("global_store_short %0, %1, off nt" :: "v"(addr), "v"(val) : "memory")
#define OSTORE4(addr, val) \
  asm volatile("global_store_dword %0, %1, off nt" :: "v"(addr), "v"(val) : "memory")
#define WAITVM(n) do { asm volatile("s_waitcnt vmcnt(" #n ")" ::: "memory"); \
                       __builtin_amdgcn_sched_barrier(0); } while (0)

// ---------- persistent bidirectional GRU layer, self-certifying h ring ----------
// r18/r19 sentinel protocol verbatim; RE-TILED 16 rows x 32 cols per block to
// halve per-CU h-ingest (32 KB/step). grid = 256 blocks x 512 threads:
// dir = bid>>7, grp = (bid>>5)&3 (16 rows), cb = bid&31 (32 cols).
// Ring: [32 slot][8 dom][32 cb] 1KB chunks ([16 rows][32 cols] bf16, row
// stride 64B). 8-wave K-split (128 k each): wave reads chunks wid*4..+3; the
// HLOAD lane map (l15*64 + l4*16) IS the 16x16x32 A-fragment layout.
__global__ __launch_bounds__(512, 1) void gru_layer(
    const uint16_t* __restrict__ xp,   // (T,B,3H) bf16 (bias already added)
    const uint16_t* __restrict__ U,    // (3H, H) bf16, rows: Ur | Uz | Un
    const float* __restrict__ bn,      // (H)
    char* __restrict__ hring,          // [32 slot][8 dom][32 cb] * 1KB = 8 MB
    uint16_t* __restrict__ out_bf,     // (T,B,2H) bf16 or null
    float* __restrict__ out_f32,       // (T,B,2H) f32 or null
    float* __restrict__ hid)           // 2 slots of (64,1024) f32: fwd then bwd
{
  __shared__ float red[8 * 96 * 20];   // 61440 B
  const int tid  = threadIdx.x;
  const int lane = tid & 63, wid = tid >> 6;   // 8 waves
  const int bid  = blockIdx.x;
  const int dir  = bid >> 7;
  const int grp  = (bid >> 5) & 3;
  const int dg   = dir * 4 + grp;      // domain 0..7
  const int cb   = bid & 31;
  const int c0   = cb * 32;
  const int brow0 = grp * 16;
  const int l15 = lane & 15, l4 = lane >> 4;
  const int gm = tid >> 5;             // gate row 0..15
  const int gc = tid & 31;             // gate col 0..31

  // register-resident B fragments: wave wid owns k = wid*128..+127;
  // 3 gates x 2 col-tiles x 4 k-chunks = 24 short8v = 96 VGPR
  short8v bfr[3][2][4];
  #pragma unroll
  for (int g = 0; g < 3; ++g)
    #pragma unroll
    for (int ct = 0; ct < 2; ++ct)
      #pragma unroll
      for (int kk = 0; kk < 4; ++kk){
        int row = g * 1024 + c0 + ct * 16 + l15;
        int k   = wid * 128 + kk * 32 + l4 * 8;
        bfr[g][ct][kk] = *(const short8v*)&U[(size_t)row * 1024 + k];
      }

  float hold = 0.f;
  const float bnv = bn[c0 + gc];

  for (int s = 0; s < 256; ++s){
    const int t = dir ? (255 - s) : s;
    const size_t xb2 = ((size_t)t * 64 + brow0 + gm) * 3072 + c0 + gc;

    f32x4 acc[3][2] = {};
    unsigned pxr, pxz, pxn;
    if (s > 0){
      const char* hgbase = hring + ((size_t)((s & 31) * 8 + dg) * 32) * 1024;

      // issue xp (oldest), then this wave's 4 h chunk loads; drain; verify.
      XPLOAD2(pxr, &xp[xb2]);
      XPLOAD2(pxz, &xp[xb2 + 1024]);
      XPLOAD2(pxn, &xp[xb2 + 2048]);
      short8v hc[4];
      #pragma unroll
      for (int kk = 0; kk < 4; ++kk)
        HLOAD(hc[kk], hgbase + (size_t)(wid * 4 + kk) * 1024 + (size_t)l15 * 64 + (size_t)l4 * 16);
      WAITVM(0);

      int spins = 0;
      for (;;){
        // packed u16 max; valid bf16 |h|<=1 -> max 0xBF80 < 0xFFFF sentinel
        u16x8 mx = (u16x8)hc[0];
        #pragma unroll
        for (int kk = 1; kk < 4; ++kk) mx = __builtin_elementwise_max(mx, (u16x8)hc[kk]);
        unsigned anybad = 0;
        #pragma unroll
        for (int i = 0; i < 8; ++i) anybad |= (unsigned)(mx[i] == (unsigned short)0xFFFFu);
        if (!__any((int)anybad)) break;
        __builtin_amdgcn_s_sleep(1);
        if (((++spins) & 255) == 0)
          __builtin_amdgcn_fence(__ATOMIC_ACQUIRE, "agent");   // safety valve
        #pragma unroll
        for (int kk = 0; kk < 4; ++kk)
          HLOAD(hc[kk], hgbase + (size_t)(wid * 4 + kk) * 1024 + (size_t)l15 * 64 + (size_t)l4 * 16);
        WAITVM(0);
      }

      // MFMA over the verified window (24 MFMAs/wave)
      #pragma unroll
      for (int kk = 0; kk < 4; ++kk)
        #pragma unroll
        for (int g = 0; g < 3; ++g)
          #pragma unroll
          for (int ct = 0; ct < 2; ++ct)
            acc[g][ct] = __builtin_amdgcn_mfma_f32_16x16x32_bf16(hc[kk], bfr[g][ct][kk], acc[g][ct], 0, 0, 0);
    } else {
      pxr = xp[xb2];
      pxz = xp[xb2 + 1024];
      pxn = xp[xb2 + 2048];
    }

    // partial sums to LDS (stride-20 swizzle; writes 2-way max = free)
    #pragma unroll
    for (int g = 0; g < 3; ++g)
      #pragma unroll
      for (int ct = 0; ct < 2; ++ct)
        *(f32x4*)&red[ridx(wid, g * 32 + ct * 16 + l15, l4 * 4)] = acc[g][ct];
    __syncthreads();                       // sync1: partials ready

    // reduce over 8 waves; thread -> (row gm, col gc)
    float ra = 0.f, za = 0.f, na = 0.f;
    #pragma unroll
    for (int w = 0; w < 8; ++w){
      ra += red[ridx(w,      gc, gm)];
      za += red[ridx(w, 32 + gc, gm)];
      na += red[ridx(w, 64 + gc, gm)];
    }
    __syncthreads();                       // sync2: red reads done (WAR safe)

    WAITVM(0);                             // xp retired; prev out drained
    float xr = bf2f((uint16_t)pxr);
    float xz = bf2f((uint16_t)pxz);
    float xn = bf2f((uint16_t)pxn);
    float r = 1.f / (1.f + __expf(-(xr + ra)));
    float z = 1.f / (1.f + __expf(-(xz + za)));
    float n = tanhf(xn + r * (na + bnv));
    float hn = (1.f - z) * n + z * hold;
    hold = hn;
    unsigned hv = f2bf(hn);

    // fire-and-forget: h -> slot (s+1)%32; sentinel re-arm -> slot (s+17)%32
    {
      const size_t mybyte = (size_t)cb * 1024 + (size_t)gm * 64 + (size_t)gc * 2;
      char* hw = hring + ((size_t)(((s + 1) & 31) * 8 + dg) * 32) * 1024 + mybyte;
      HSTORE2(hw, hv);
      char* sw = hring + ((size_t)(((s + 17) & 31) * 8 + dg) * 32) * 1024 + mybyte;
      HSTORE2(sw, 0xFFFFu);
    }

    // out store (drains inside next step's WAITVM(0))
    {
      size_t obase = ((size_t)t * 64 + brow0 + gm) * 2048 + (size_t)dir * 1024 + c0 + gc;
      if (out_bf) OSTORE2(&out_bf[obase], hv);
      else        OSTORE4(&out_f32[obase], __float_as_uint(hn));
      if (s == 255)
        hid[((size_t)dir * 64 + brow0 + gm) * 1024 + c0 + gc] = hn;
    }
  }
}

// ---------- host ----------
extern "C" void kernel_launch(void* const* d_in, const int* in_sizes, int n_in,
                              void* d_out, int out_size, void* d_ws, size_t ws_size,
                              hipStream_t stream) {
  const float* x   = (const float*)d_in[0];
  const float* W0  = (const float*)d_in[1];
  const float* b0  = (const float*)d_in[2];
  const float* Ur0 = (const float*)d_in[3];
  const float* Uz0 = (const float*)d_in[4];
  const float* Un0 = (const float*)d_in[5];
  const float* bn0 = (const float*)d_in[6];
  const float* W1  = (const float*)d_in[7];
  const float* b1  = (const float*)d_in[8];
  const float* Ur1 = (const float*)d_in[9];
  const float* Uz1 = (const float*)d_in[10];
  const float* Un1 = (const float*)d_in[11];
  const float* bn1 = (const float*)d_in[12];
  float* out = (float*)d_out;

  const size_t RING = (size_t)8 * 1024 * 1024;   // 32 slots x 8 domains x 32KB
  char* base = (char*)d_ws;
  char*     hring = base;
  uint16_t* xb    = (uint16_t*)(base + RING);
  uint16_t* w0b   = xb    + (size_t)16384 * 1024;
  uint16_t* u0b   = w0b   + (size_t)3072 * 1024;
  uint16_t* w1b   = u0b   + (size_t)3072 * 1024;
  uint16_t* u1b   = w1b   + (size_t)3072 * 2048;
  uint16_t* xp    = u1b   + (size_t)3072 * 1024;
  uint16_t* out0b = xp    + (size_t)16384 * 3072;

  auto cvt = [&](const float* s, uint16_t* d, size_t n){
    int n4 = (int)(n / 4);
    int grid = (n4 + 255) / 256; if (grid > 2048) grid = 2048;
    hipLaunchKernelGGL(cvt_f32_bf16, dim3(grid), dim3(256), 0, stream, s, d, n4);
  };
  // sentinel-fill the ring for layer 0 (in-graph, replayed each call)
  hipMemsetAsync(hring, 0xFF, RING, stream);

  cvt(x,   xb,  (size_t)16384 * 1024);
  cvt(W0,  w0b, (size_t)3072 * 1024);
  cvt(Ur0, u0b + 0 * (size_t)1024 * 1024, (size_t)1024 * 1024);
  cvt(Uz0, u0b + 1 * (size_t)1024 * 1024, (size_t)1024 * 1024);
  cvt(Un0, u0b + 2 * (size_t)1024 * 1024, (size_t)1024 * 1024);
  cvt(W1,  w1b, (size_t)3072 * 2048);
  cvt(Ur1, u1b + 0 * (size_t)1024 * 1024, (size_t)1024 * 1024);
  cvt(Uz1, u1b + 1 * (size_t)1024 * 1024, (size_t)1024 * 1024);
  cvt(Un1, u1b + 2 * (size_t)1024 * 1024, (size_t)1024 * 1024);

  // layer 0: xp0 = x @ W0^T + b0
  hipLaunchKernelGGL(gemm_bt_bias, dim3(24, 128), dim3(256), 0, stream,
                     xb, w0b, b0, xp, 16384, 3072, 1024);
  // layer 0 recurrence -> out0b (bf16), hidden slots 0,1
  hipLaunchKernelGGL(gru_layer, dim3(256), dim3(512), 0, stream,
                     xp, u0b, bn0, hring,
                     out0b, (float*)nullptr,
                     out + (size_t)33554432);
  // re-sentinel the ring for layer 1 (stream-ordered after layer 0)
  hipMemsetAsync(hring, 0xFF, RING, stream);
  // layer 1: xp1 = out0 @ W1^T + b1
  hipLaunchKernelGGL(gemm_bt_bias, dim3(24, 128), dim3(256), 0, stream,
                     out0b, w1b, b1, xp, 16384, 3072, 2048);
  // layer 1 recurrence -> d_out (f32), hidden slots 2,3
  hipLaunchKernelGGL(gru_layer, dim3(256), dim3(512), 0, stream,
                     xp, u1b, bn1, hring,
                     (uint16_t*)nullptr, out,
                     out + (size_t)33554432 + (size_t)2 * 64 * 1024);
}

// Round 21
// 2208.602 us; speedup vs baseline: 1.3051x; 1.3051x over previous
//
#include <hip/hip_runtime.h>
#include <stdint.h>

// ---------- types ----------
typedef short short8v __attribute__((ext_vector_type(8)));
typedef unsigned short u16x8 __attribute__((ext_vector_type(8)));
typedef float f32x4  __attribute__((ext_vector_type(4)));
typedef unsigned long long u64;

__device__ inline uint16_t f2bf(float f){
  uint32_t u = __float_as_uint(f);
  uint32_t r = (u + 0x7fffu + ((u >> 16) & 1u)) >> 16;
  return (uint16_t)r;
}
__device__ inline float bf2f(uint16_t h){
  return __uint_as_float(((uint32_t)h) << 16);
}

// ---------- f32 -> bf16 conversion (vectorized) ----------
__global__ void cvt_f32_bf16(const float* __restrict__ src, uint16_t* __restrict__ dst, int n4){
  int i = blockIdx.x * blockDim.x + threadIdx.x;
  int stride = gridDim.x * blockDim.x;
  for (; i < n4; i += stride){
    float4 v = ((const float4*)src)[i];
    uint64_t p = (uint64_t)f2bf(v.x)
               | ((uint64_t)f2bf(v.y) << 16)
               | ((uint64_t)f2bf(v.z) << 32)
               | ((uint64_t)f2bf(v.w) << 48);
    ((uint64_t*)dst)[i] = p;
  }
}

// ---------- bf16 GEMM: C[m,n] = sum_k A[m,k] * Bw[n,k] + bias[n]  (C bf16) ----------
#define GL2LDS(g, l) __builtin_amdgcn_global_load_lds((const __attribute__((address_space(1))) unsigned int*)(g), (__attribute__((address_space(3))) unsigned int*)(l), 16, 0, 0)

__global__ __launch_bounds__(256) void gemm_bt_bias(
    const uint16_t* __restrict__ A, const uint16_t* __restrict__ Bw,
    const float* __restrict__ bias, uint16_t* __restrict__ C,
    int M, int N, int K)
{
  __shared__ uint16_t As[128 * 64];
  __shared__ uint16_t Bs[128 * 64];
  const int tid  = threadIdx.x;
  const int lane = tid & 63, wid = tid >> 6;
  const int n0 = blockIdx.x * 128, m0 = blockIdx.y * 128;
  const int wrow = (wid & 1) * 64, wcol = (wid >> 1) * 64;
  const int l15 = lane & 15, l4 = lane >> 4;
  const int srow = lane >> 3, scol = (lane & 7) * 8;
  const size_t Ks = (size_t)K;

  f32x4 acc[4][4] = {};

  for (int kt = 0; kt < K; kt += 64){
    __syncthreads();
    const uint16_t* gA = A  + (size_t)m0 * Ks + kt;
    const uint16_t* gB = Bw + (size_t)n0 * Ks + kt;
    #pragma unroll
    for (int i = 0; i < 4; ++i){
      int rb = wid * 32 + i * 8;
      GL2LDS(gA + (size_t)(rb + srow) * Ks + scol, &As[rb * 64]);
      GL2LDS(gB + (size_t)(rb + srow) * Ks + scol, &Bs[rb * 64]);
    }
    __syncthreads();
    #pragma unroll
    for (int kk = 0; kk < 2; ++kk){
      short8v a[4], b[4];
      int koff = kk * 32 + l4 * 8;
      #pragma unroll
      for (int mt = 0; mt < 4; ++mt) a[mt] = *(const short8v*)&As[(wrow + mt*16 + l15) * 64 + koff];
      #pragma unroll
      for (int nt = 0; nt < 4; ++nt) b[nt] = *(const short8v*)&Bs[(wcol + nt*16 + l15) * 64 + koff];
      #pragma unroll
      for (int mt = 0; mt < 4; ++mt)
        #pragma unroll
        for (int nt = 0; nt < 4; ++nt)
          acc[mt][nt] = __builtin_amdgcn_mfma_f32_16x16x32_bf16(a[mt], b[nt], acc[mt][nt], 0, 0, 0);
    }
  }
  #pragma unroll
  for (int mt = 0; mt < 4; ++mt)
    #pragma unroll
    for (int nt = 0; nt < 4; ++nt){
      int col = n0 + wcol + nt * 16 + l15;
      float bv = bias[col];
      int rbase = m0 + wrow + mt * 16 + l4 * 4;
      #pragma unroll
      for (int j = 0; j < 4; ++j)
        C[(size_t)(rbase + j) * (size_t)N + col] = f2bf(acc[mt][nt][j] + bv);
    }
}

// LDS reduce index: r19's PROVEN geometry — [8 waves][48 = 3 gates x 16 cols]
// [stride 40 f32], m-axis = coltile*16 + row (0..31). f32x4 writes conflict-
// free, reads 16c x 4m spread (measured 2.5e7 in r19 vs 3.27e8 for r20's
// stride-20 variant whose XOR cancelled odd bank residues).
__device__ inline int ridx8(int w, int c, int m){
  return (w * 48 + c) * 40 + (m ^ ((c & 7) << 2));
}

// 16B MALL-direct load (bypass L1+L2) — proven r4/r10
#define HLOAD(dst, addr) \
  asm volatile("global_load_dwordx4 %0, %1, off sc0 sc1" : "=v"(dst) : "v"(addr) : "memory")
// plain cached 2B load (xp)
#define XPLOAD2(dst, addr) \
  asm volatile("global_load_ushort %0, %1, off" : "=v"(dst) : "v"(addr) : "memory")
// write-through 2B store (h / sentinel), fire-and-forget
#define HSTORE2(addr, val) \
  asm volatile("global_store_short %0, %1, off sc0 sc1" :: "v"(addr), "v"(val) : "memory")
#define OSTORE2(addr, val) \
  asm volatile("global_store_short %0, %1, off nt" :: "v"(addr), "v"(val) : "memory")
#define OSTORE4(addr, val) \
  asm volatile("global_store_dword %0, %1, off nt" :: "v"(addr), "v"(val) : "memory")
#define WAITVM(n) do { asm volatile("s_waitcnt vmcnt(" #n ")" ::: "memory"); \
                       __builtin_amdgcn_sched_barrier(0); } while (0)

// ---------- persistent bidirectional GRU layer, self-certifying h ring ----------
// r20 structure (16 rows x 32 cols tile, halved per-CU ingest — FETCH_SIZE
// confirmed 528 MB) with the LDS reduce restored to r19's proven shape.
// grid = 256 blocks x 512 threads: dir = bid>>7, grp = (bid>>5)&3, cb = bid&31.
// Ring: [32 slot][8 dom][32 cb] 1KB chunks ([16 rows][32 cols] bf16).
__global__ __launch_bounds__(512, 1) void gru_layer(
    const uint16_t* __restrict__ xp,   // (T,B,3H) bf16 (bias already added)
    const uint16_t* __restrict__ U,    // (3H, H) bf16, rows: Ur | Uz | Un
    const float* __restrict__ bn,      // (H)
    char* __restrict__ hring,          // [32 slot][8 dom][32 cb] * 1KB = 8 MB
    uint16_t* __restrict__ out_bf,     // (T,B,2H) bf16 or null
    float* __restrict__ out_f32,       // (T,B,2H) f32 or null
    float* __restrict__ hid)           // 2 slots of (64,1024) f32: fwd then bwd
{
  __shared__ float red[8 * 48 * 40];   // 61440 B
  const int tid  = threadIdx.x;
  const int lane = tid & 63, wid = tid >> 6;   // 8 waves
  const int bid  = blockIdx.x;
  const int dir  = bid >> 7;
  const int grp  = (bid >> 5) & 3;
  const int dg   = dir * 4 + grp;      // domain 0..7
  const int cb   = bid & 31;
  const int c0   = cb * 32;
  const int brow0 = grp * 16;
  const int l15 = lane & 15, l4 = lane >> 4;
  const int gm = tid >> 5;             // gate row 0..15
  const int gc = tid & 31;             // gate col 0..31
  const int rc = gc & 15;              // red col-within-gate
  const int rm = (gc >> 4) * 16 + gm;  // red m-axis = coltile*16 + row

  // register-resident B fragments: wave wid owns k = wid*128..+127;
  // 3 gates x 2 col-tiles x 4 k-chunks = 24 short8v = 96 VGPR
  short8v bfr[3][2][4];
  #pragma unroll
  for (int g = 0; g < 3; ++g)
    #pragma unroll
    for (int ct = 0; ct < 2; ++ct)
      #pragma unroll
      for (int kk = 0; kk < 4; ++kk){
        int row = g * 1024 + c0 + ct * 16 + l15;
        int k   = wid * 128 + kk * 32 + l4 * 8;
        bfr[g][ct][kk] = *(const short8v*)&U[(size_t)row * 1024 + k];
      }

  float hold = 0.f;
  const float bnv = bn[c0 + gc];

  for (int s = 0; s < 256; ++s){
    const int t = dir ? (255 - s) : s;
    const size_t xb2 = ((size_t)t * 64 + brow0 + gm) * 3072 + c0 + gc;

    f32x4 acc[3][2] = {};
    unsigned pxr, pxz, pxn;
    if (s > 0){
      const char* hgbase = hring + ((size_t)((s & 31) * 8 + dg) * 32) * 1024;

      // issue xp (oldest), then this wave's 4 h chunk loads; drain; verify.
      XPLOAD2(pxr, &xp[xb2]);
      XPLOAD2(pxz, &xp[xb2 + 1024]);
      XPLOAD2(pxn, &xp[xb2 + 2048]);
      short8v hc[4];
      #pragma unroll
      for (int kk = 0; kk < 4; ++kk)
        HLOAD(hc[kk], hgbase + (size_t)(wid * 4 + kk) * 1024 + (size_t)l15 * 64 + (size_t)l4 * 16);
      WAITVM(0);

      int spins = 0;
      for (;;){
        // packed u16 max; valid bf16 |h|<=1 -> max 0xBF80 < 0xFFFF sentinel
        u16x8 mx = (u16x8)hc[0];
        #pragma unroll
        for (int kk = 1; kk < 4; ++kk) mx = __builtin_elementwise_max(mx, (u16x8)hc[kk]);
        unsigned anybad = 0;
        #pragma unroll
        for (int i = 0; i < 8; ++i) anybad |= (unsigned)(mx[i] == (unsigned short)0xFFFFu);
        if (!__any((int)anybad)) break;
        __builtin_amdgcn_s_sleep(1);
        if (((++spins) & 255) == 0)
          __builtin_amdgcn_fence(__ATOMIC_ACQUIRE, "agent");   // safety valve
        #pragma unroll
        for (int kk = 0; kk < 4; ++kk)
          HLOAD(hc[kk], hgbase + (size_t)(wid * 4 + kk) * 1024 + (size_t)l15 * 64 + (size_t)l4 * 16);
        WAITVM(0);
      }

      // MFMA over the verified window (24 MFMAs/wave)
      #pragma unroll
      for (int kk = 0; kk < 4; ++kk)
        #pragma unroll
        for (int g = 0; g < 3; ++g)
          #pragma unroll
          for (int ct = 0; ct < 2; ++ct)
            acc[g][ct] = __builtin_amdgcn_mfma_f32_16x16x32_bf16(hc[kk], bfr[g][ct][kk], acc[g][ct], 0, 0, 0);
    } else {
      pxr = xp[xb2];
      pxz = xp[xb2 + 1024];
      pxn = xp[xb2 + 2048];
    }

    // partial sums to LDS — r19's proven write pattern (c=g*16+l15, m=ct*16+l4*4)
    #pragma unroll
    for (int g = 0; g < 3; ++g)
      #pragma unroll
      for (int ct = 0; ct < 2; ++ct)
        *(f32x4*)&red[ridx8(wid, g * 16 + l15, ct * 16 + l4 * 4)] = acc[g][ct];
    __syncthreads();                       // sync1: partials ready

    // reduce over 8 waves — r19's proven read pattern (16c x 4m per wave)
    float ra = 0.f, za = 0.f, na = 0.f;
    #pragma unroll
    for (int w = 0; w < 8; ++w){
      ra += red[ridx8(w,      rc, rm)];
      za += red[ridx8(w, 16 + rc, rm)];
      na += red[ridx8(w, 32 + rc, rm)];
    }
    __syncthreads();                       // sync2: red reads done (WAR safe)

    WAITVM(0);                             // xp retired; prev out drained
    float xr = bf2f((uint16_t)pxr);
    float xz = bf2f((uint16_t)pxz);
    float xn = bf2f((uint16_t)pxn);
    float r = 1.f / (1.f + __expf(-(xr + ra)));
    float z = 1.f / (1.f + __expf(-(xz + za)));
    float n = tanhf(xn + r * (na + bnv));
    float hn = (1.f - z) * n + z * hold;
    hold = hn;
    unsigned hv = f2bf(hn);

    // fire-and-forget: h -> slot (s+1)%32; sentinel re-arm -> slot (s+17)%32
    {
      const size_t mybyte = (size_t)cb * 1024 + (size_t)gm * 64 + (size_t)gc * 2;
      char* hw = hring + ((size_t)(((s + 1) & 31) * 8 + dg) * 32) * 1024 + mybyte;
      HSTORE2(hw, hv);
      char* sw = hring + ((size_t)(((s + 17) & 31) * 8 + dg) * 32) * 1024 + mybyte;
      HSTORE2(sw, 0xFFFFu);
    }

    // out store (drains inside next step's WAITVM(0))
    {
      size_t obase = ((size_t)t * 64 + brow0 + gm) * 2048 + (size_t)dir * 1024 + c0 + gc;
      if (out_bf) OSTORE2(&out_bf[obase], hv);
      else        OSTORE4(&out_f32[obase], __float_as_uint(hn));
      if (s == 255)
        hid[((size_t)dir * 64 + brow0 + gm) * 1024 + c0 + gc] = hn;
    }
  }
}

// ---------- host ----------
extern "C" void kernel_launch(void* const* d_in, const int* in_sizes, int n_in,
                              void* d_out, int out_size, void* d_ws, size_t ws_size,
                              hipStream_t stream) {
  const float* x   = (const float*)d_in[0];
  const float* W0  = (const float*)d_in[1];
  const float* b0  = (const float*)d_in[2];
  const float* Ur0 = (const float*)d_in[3];
  const float* Uz0 = (const float*)d_in[4];
  const float* Un0 = (const float*)d_in[5];
  const float* bn0 = (const float*)d_in[6];
  const float* W1  = (const float*)d_in[7];
  const float* b1  = (const float*)d_in[8];
  const float* Ur1 = (const float*)d_in[9];
  const float* Uz1 = (const float*)d_in[10];
  const float* Un1 = (const float*)d_in[11];
  const float* bn1 = (const float*)d_in[12];
  float* out = (float*)d_out;

  const size_t RING = (size_t)8 * 1024 * 1024;   // 32 slots x 8 domains x 32KB
  char* base = (char*)d_ws;
  char*     hring = base;
  uint16_t* xb    = (uint16_t*)(base + RING);
  uint16_t* w0b   = xb    + (size_t)16384 * 1024;
  uint16_t* u0b   = w0b   + (size_t)3072 * 1024;
  uint16_t* w1b   = u0b   + (size_t)3072 * 1024;
  uint16_t* u1b   = w1b   + (size_t)3072 * 2048;
  uint16_t* xp    = u1b   + (size_t)3072 * 1024;
  uint16_t* out0b = xp    + (size_t)16384 * 3072;

  auto cvt = [&](const float* s, uint16_t* d, size_t n){
    int n4 = (int)(n / 4);
    int grid = (n4 + 255) / 256; if (grid > 2048) grid = 2048;
    hipLaunchKernelGGL(cvt_f32_bf16, dim3(grid), dim3(256), 0, stream, s, d, n4);
  };
  // sentinel-fill the ring for layer 0 (in-graph, replayed each call)
  hipMemsetAsync(hring, 0xFF, RING, stream);

  cvt(x,   xb,  (size_t)16384 * 1024);
  cvt(W0,  w0b, (size_t)3072 * 1024);
  cvt(Ur0, u0b + 0 * (size_t)1024 * 1024, (size_t)1024 * 1024);
  cvt(Uz0, u0b + 1 * (size_t)1024 * 1024, (size_t)1024 * 1024);
  cvt(Un0, u0b + 2 * (size_t)1024 * 1024, (size_t)1024 * 1024);
  cvt(W1,  w1b, (size_t)3072 * 2048);
  cvt(Ur1, u1b + 0 * (size_t)1024 * 1024, (size_t)1024 * 1024);
  cvt(Uz1, u1b + 1 * (size_t)1024 * 1024, (size_t)1024 * 1024);
  cvt(Un1, u1b + 2 * (size_t)1024 * 1024, (size_t)1024 * 1024);

  // layer 0: xp0 = x @ W0^T + b0
  hipLaunchKernelGGL(gemm_bt_bias, dim3(24, 128), dim3(256), 0, stream,
                     xb, w0b, b0, xp, 16384, 3072, 1024);
  // layer 0 recurrence -> out0b (bf16), hidden slots 0,1
  hipLaunchKernelGGL(gru_layer, dim3(256), dim3(512), 0, stream,
                     xp, u0b, bn0, hring,
                     out0b, (float*)nullptr,
                     out + (size_t)33554432);
  // re-sentinel the ring for layer 1 (stream-ordered after layer 0)
  hipMemsetAsync(hring, 0xFF, RING, stream);
  // layer 1: xp1 = out0 @ W1^T + b1
  hipLaunchKernelGGL(gemm_bt_bias, dim3(24, 128), dim3(256), 0, stream,
                     out0b, w1b, b1, xp, 16384, 3072, 2048);
  // layer 1 recurrence -> d_out (f32), hidden slots 2,3
  hipLaunchKernelGGL(gru_layer, dim3(256), dim3(512), 0, stream,
                     xp, u1b, bn1, hring,
                     (uint16_t*)nullptr, out,
                     out + (size_t)33554432 + (size_t)2 * 64 * 1024);
}

// Round 22
// 2129.329 us; speedup vs baseline: 1.3537x; 1.0372x over previous
//
#include <hip/hip_runtime.h>
#include <stdint.h>

// ---------- types ----------
typedef short short8v __attribute__((ext_vector_type(8)));
typedef unsigned short u16x8 __attribute__((ext_vector_type(8)));
typedef float f32x4  __attribute__((ext_vector_type(4)));
typedef unsigned long long u64;

__device__ inline uint16_t f2bf(float f){
  uint32_t u = __float_as_uint(f);
  uint32_t r = (u + 0x7fffu + ((u >> 16) & 1u)) >> 16;
  return (uint16_t)r;
}
__device__ inline float bf2f(uint16_t h){
  return __uint_as_float(((uint32_t)h) << 16);
}

// ---------- f32 -> bf16 conversion (vectorized) ----------
__global__ void cvt_f32_bf16(const float* __restrict__ src, uint16_t* __restrict__ dst, int n4){
  int i = blockIdx.x * blockDim.x + threadIdx.x;
  int stride = gridDim.x * blockDim.x;
  for (; i < n4; i += stride){
    float4 v = ((const float4*)src)[i];
    uint64_t p = (uint64_t)f2bf(v.x)
               | ((uint64_t)f2bf(v.y) << 16)
               | ((uint64_t)f2bf(v.z) << 32)
               | ((uint64_t)f2bf(v.w) << 48);
    ((uint64_t*)dst)[i] = p;
  }
}

// ---------- bf16 GEMM: C[m,n] = sum_k A[m,k] * Bw[n,k] + bias[n]  (C bf16) ----------
// 1-D grid of 3072 blocks with bijective XCD swizzle (3072 % 8 == 0):
// each XCD gets 384 consecutive wgids -> contiguous m-tiles share A-panels in
// its private L2 (m192: +10% when HBM-bound).
#define GL2LDS(g, l) __builtin_amdgcn_global_load_lds((const __attribute__((address_space(1))) unsigned int*)(g), (__attribute__((address_space(3))) unsigned int*)(l), 16, 0, 0)

__global__ __launch_bounds__(256) void gemm_bt_bias(
    const uint16_t* __restrict__ A, const uint16_t* __restrict__ Bw,
    const float* __restrict__ bias, uint16_t* __restrict__ C,
    int M, int N, int K)
{
  __shared__ uint16_t As[128 * 64];
  __shared__ uint16_t Bs[128 * 64];
  const int tid  = threadIdx.x;
  const int lane = tid & 63, wid = tid >> 6;
  const int swz  = (blockIdx.x & 7) * 384 + (blockIdx.x >> 3);   // bijective
  const int n0 = (swz % 24) * 128, m0 = (swz / 24) * 128;
  const int wrow = (wid & 1) * 64, wcol = (wid >> 1) * 64;
  const int l15 = lane & 15, l4 = lane >> 4;
  const int srow = lane >> 3, scol = (lane & 7) * 8;
  const size_t Ks = (size_t)K;

  f32x4 acc[4][4] = {};

  for (int kt = 0; kt < K; kt += 64){
    __syncthreads();
    const uint16_t* gA = A  + (size_t)m0 * Ks + kt;
    const uint16_t* gB = Bw + (size_t)n0 * Ks + kt;
    #pragma unroll
    for (int i = 0; i < 4; ++i){
      int rb = wid * 32 + i * 8;
      GL2LDS(gA + (size_t)(rb + srow) * Ks + scol, &As[rb * 64]);
      GL2LDS(gB + (size_t)(rb + srow) * Ks + scol, &Bs[rb * 64]);
    }
    __syncthreads();
    #pragma unroll
    for (int kk = 0; kk < 2; ++kk){
      short8v a[4], b[4];
      int koff = kk * 32 + l4 * 8;
      #pragma unroll
      for (int mt = 0; mt < 4; ++mt) a[mt] = *(const short8v*)&As[(wrow + mt*16 + l15) * 64 + koff];
      #pragma unroll
      for (int nt = 0; nt < 4; ++nt) b[nt] = *(const short8v*)&Bs[(wcol + nt*16 + l15) * 64 + koff];
      #pragma unroll
      for (int mt = 0; mt < 4; ++mt)
        #pragma unroll
        for (int nt = 0; nt < 4; ++nt)
          acc[mt][nt] = __builtin_amdgcn_mfma_f32_16x16x32_bf16(a[mt], b[nt], acc[mt][nt], 0, 0, 0);
    }
  }
  #pragma unroll
  for (int mt = 0; mt < 4; ++mt)
    #pragma unroll
    for (int nt = 0; nt < 4; ++nt){
      int col = n0 + wcol + nt * 16 + l15;
      float bv = bias[col];
      int rbase = m0 + wrow + mt * 16 + l4 * 4;
      #pragma unroll
      for (int j = 0; j < 4; ++j)
        C[(size_t)(rbase + j) * (size_t)N + col] = f2bf(acc[mt][nt][j] + bv);
    }
}

// LDS reduce index, stride 40 f32, 8 waves (r19-proven: f32x4 writes
// conflict-free; reads 16c x 4m spread, measured 2.5e7/dispatch).
__device__ inline int ridx8(int w, int c, int m){
  return (w * 48 + c) * 40 + (m ^ ((c & 7) << 2));
}

// 16B MALL-direct load (bypass L1+L2) — proven r4/r10
#define HLOAD(dst, addr) \
  asm volatile("global_load_dwordx4 %0, %1, off sc0 sc1" : "=v"(dst) : "v"(addr) : "memory")
// plain cached 2B load (xp)
#define XPLOAD2(dst, addr) \
  asm volatile("global_load_ushort %0, %1, off" : "=v"(dst) : "v"(addr) : "memory")
// write-through 2B store (h / sentinel), fire-and-forget
#define HSTORE2(addr, val) \
  asm volatile("global_store_short %0, %1, off sc0 sc1" :: "v"(addr), "v"(val) : "memory")
#define OSTORE2(addr, val) \
  asm volatile("global_store_short %0, %1, off nt" :: "v"(addr), "v"(val) : "memory")
#define OSTORE4(addr, val) \
  asm volatile("global_store_dword %0, %1, off nt" :: "v"(addr), "v"(val) : "memory")
#define WAITVM(n) do { asm volatile("s_waitcnt vmcnt(" #n ")" ::: "memory"); \
                       __builtin_amdgcn_sched_barrier(0); } while (0)

// ---------- persistent bidirectional GRU layer, self-certifying h ring ----------
// r19 VERBATIM (best measured: 836 us/layer). 32-slot sentinel ring,
// fire-and-forget h + sentinel re-arm 16 steps ahead, per-wave data-verify
// (packed u16-max) with retry. 512-thread blocks, 8-wave K-split (128 k each).
// grid = 256 blocks: dir = bid>>7, grp = (bid>>6)&1 (32 rows), cb = bid&63.
__global__ __launch_bounds__(512, 1) void gru_layer(
    const uint16_t* __restrict__ xp,   // (T,B,3H) bf16 (bias already added)
    const uint16_t* __restrict__ U,    // (3H, H) bf16, rows: Ur | Uz | Un
    const float* __restrict__ bn,      // (H)
    char* __restrict__ hring,          // [32 slot][4 dom][64 cb] * 1KB = 8 MB
    uint16_t* __restrict__ out_bf,     // (T,B,2H) bf16 or null
    float* __restrict__ out_f32,       // (T,B,2H) f32 or null
    float* __restrict__ hid)           // 2 slots of (64,1024) f32: fwd then bwd
{
  __shared__ float red[8 * 48 * 40];   // 61440 B
  const int tid  = threadIdx.x;
  const int lane = tid & 63, wid = tid >> 6;   // 8 waves
  const int bid  = blockIdx.x;
  const int dir  = bid >> 7;
  const int grp  = (bid >> 6) & 1;
  const int dg   = dir * 2 + grp;      // domain 0..3
  const int cb   = bid & 63;
  const int c0   = cb * 16;
  const int brow0 = grp * 32;
  const int l15 = lane & 15, l4 = lane >> 4;
  const int gm = tid >> 4;             // gate row 0..31
  const int c16 = tid & 15;            // gate col 0..15

  // register-resident B fragments (U weights): wave wid owns k = wid*128..+127
  short8v bfr[3][4];
  #pragma unroll
  for (int g = 0; g < 3; ++g)
    #pragma unroll
    for (int kk = 0; kk < 4; ++kk){
      int row = g * 1024 + c0 + l15;
      int k   = wid * 128 + kk * 32 + l4 * 8;
      bfr[g][kk] = *(const short8v*)&U[(size_t)row * 1024 + k];
    }

  float hold = 0.f;
  const float bnv = bn[c0 + c16];

  // consumer h geometry: chunk = wid*8 + kk*2 + (l4>>1);
  // byte = chunk*1024 + (l4&1)*16 + l15*32 ; mt selects 16-row half (+512B)
  const size_t hoff = (size_t)(wid * 8 + (l4 >> 1)) * 1024 + (size_t)(l4 & 1) * 16 + (size_t)l15 * 32;

  for (int s = 0; s < 256; ++s){
    const int t = dir ? (255 - s) : s;
    const size_t xb2 = ((size_t)t * 64 + brow0 + gm) * 3072 + c0 + c16;

    f32x4 acc[3][2] = {};
    unsigned pxr, pxz, pxn;
    if (s > 0){
      const char* hgbase = hring + ((size_t)((s & 31) * 4 + dg) * 64) * 1024;

      // issue xp (oldest), then this wave's 8 h loads; drain; verify; retry.
      XPLOAD2(pxr, &xp[xb2]);
      XPLOAD2(pxz, &xp[xb2 + 1024]);
      XPLOAD2(pxn, &xp[xb2 + 2048]);
      short8v hc[4][2];
      #pragma unroll
      for (int kk = 0; kk < 4; ++kk)
        #pragma unroll
        for (int mt = 0; mt < 2; ++mt)
          HLOAD(hc[kk][mt], hgbase + hoff + (size_t)kk * 2048 + (size_t)mt * 512);
      WAITVM(0);

      int spins = 0;
      for (;;){
        // packed u16 max; valid bf16 |h|<=1 -> max 0xBF80 < 0xFFFF sentinel
        u16x8 mx = (u16x8)hc[0][0];
        #pragma unroll
        for (int kk = 0; kk < 4; ++kk)
          #pragma unroll
          for (int mt = 0; mt < 2; ++mt)
            if (kk | mt) mx = __builtin_elementwise_max(mx, (u16x8)hc[kk][mt]);
        unsigned anybad = 0;
        #pragma unroll
        for (int i = 0; i < 8; ++i) anybad |= (unsigned)(mx[i] == (unsigned short)0xFFFFu);
        if (!__any((int)anybad)) break;
        __builtin_amdgcn_s_sleep(1);
        if (((++spins) & 255) == 0)
          __builtin_amdgcn_fence(__ATOMIC_ACQUIRE, "agent");   // safety valve
        #pragma unroll
        for (int kk = 0; kk < 4; ++kk)
          #pragma unroll
          for (int mt = 0; mt < 2; ++mt)
            HLOAD(hc[kk][mt], hgbase + hoff + (size_t)kk * 2048 + (size_t)mt * 512);
        WAITVM(0);
      }

      // MFMA over the verified window (24 MFMAs/wave)
      #pragma unroll
      for (int kk = 0; kk < 4; ++kk)
        #pragma unroll
        for (int g = 0; g < 3; ++g)
          #pragma unroll
          for (int mt = 0; mt < 2; ++mt)
            acc[g][mt] = __builtin_amdgcn_mfma_f32_16x16x32_bf16(hc[kk][mt], bfr[g][kk], acc[g][mt], 0, 0, 0);
    } else {
      pxr = xp[xb2];
      pxz = xp[xb2 + 1024];
      pxn = xp[xb2 + 2048];
    }

    // partial sums to LDS (8-wave stride-40 swizzle, conflict-free writes)
    #pragma unroll
    for (int g = 0; g < 3; ++g)
      #pragma unroll
      for (int mt = 0; mt < 2; ++mt)
        *(f32x4*)&red[ridx8(wid, g * 16 + l15, mt * 16 + l4 * 4)] = acc[g][mt];
    __syncthreads();                       // sync1: partials ready

    // reduce over 8 waves; thread -> (row gm, col c16)
    float ra = 0.f, za = 0.f, na = 0.f;
    #pragma unroll
    for (int w = 0; w < 8; ++w){
      ra += red[ridx8(w,      c16, gm)];
      za += red[ridx8(w, 16 + c16, gm)];
      na += red[ridx8(w, 32 + c16, gm)];
    }
    __syncthreads();                       // sync2: red reads done (WAR safe)

    WAITVM(0);                             // xp retired (s==0 path too)
    float xr = bf2f((uint16_t)pxr);
    float xz = bf2f((uint16_t)pxz);
    float xn = bf2f((uint16_t)pxn);
    float r = 1.f / (1.f + __expf(-(xr + ra)));
    float z = 1.f / (1.f + __expf(-(xz + za)));
    float n = tanhf(xn + r * (na + bnv));
    float hn = (1.f - z) * n + z * hold;
    hold = hn;
    unsigned hv = f2bf(hn);

    // fire-and-forget: h -> slot (s+1)%32; sentinel re-arm -> slot (s+17)%32
    {
      const size_t mybyte = (size_t)cb * 1024 + (size_t)gm * 32 + (size_t)c16 * 2;
      char* hw = hring + ((size_t)(((s + 1) & 31) * 4 + dg) * 64) * 1024 + mybyte;
      HSTORE2(hw, hv);
      char* sw = hring + ((size_t)(((s + 17) & 31) * 4 + dg) * 64) * 1024 + mybyte;
      HSTORE2(sw, 0xFFFFu);
    }

    // out store (drains inside next step's WAITVM(0))
    {
      size_t obase = ((size_t)t * 64 + brow0 + gm) * 2048 + (size_t)dir * 1024 + c0 + c16;
      if (out_bf) OSTORE2(&out_bf[obase], hv);
      else        OSTORE4(&out_f32[obase], __float_as_uint(hn));
      if (s == 255)
        hid[((size_t)dir * 64 + brow0 + gm) * 1024 + c0 + c16] = hn;
    }
  }
}

// ---------- host ----------
extern "C" void kernel_launch(void* const* d_in, const int* in_sizes, int n_in,
                              void* d_out, int out_size, void* d_ws, size_t ws_size,
                              hipStream_t stream) {
  const float* x   = (const float*)d_in[0];
  const float* W0  = (const float*)d_in[1];
  const float* b0  = (const float*)d_in[2];
  const float* Ur0 = (const float*)d_in[3];
  const float* Uz0 = (const float*)d_in[4];
  const float* Un0 = (const float*)d_in[5];
  const float* bn0 = (const float*)d_in[6];
  const float* W1  = (const float*)d_in[7];
  const float* b1  = (const float*)d_in[8];
  const float* Ur1 = (const float*)d_in[9];
  const float* Uz1 = (const float*)d_in[10];
  const float* Un1 = (const float*)d_in[11];
  const float* bn1 = (const float*)d_in[12];
  float* out = (float*)d_out;

  const size_t RING = (size_t)8 * 1024 * 1024;   // 32 slots x 4 domains x 64KB
  char* base = (char*)d_ws;
  char*     hring = base;
  uint16_t* xb    = (uint16_t*)(base + RING);
  uint16_t* w0b   = xb    + (size_t)16384 * 1024;
  uint16_t* u0b   = w0b   + (size_t)3072 * 1024;
  uint16_t* w1b   = u0b   + (size_t)3072 * 1024;
  uint16_t* u1b   = w1b   + (size_t)3072 * 2048;
  uint16_t* xp    = u1b   + (size_t)3072 * 1024;
  uint16_t* out0b = xp    + (size_t)16384 * 3072;

  auto cvt = [&](const float* s, uint16_t* d, size_t n){
    int n4 = (int)(n / 4);
    int grid = (n4 + 255) / 256; if (grid > 2048) grid = 2048;
    hipLaunchKernelGGL(cvt_f32_bf16, dim3(grid), dim3(256), 0, stream, s, d, n4);
  };
  // sentinel-fill the ring for layer 0 (in-graph, replayed each call)
  hipMemsetAsync(hring, 0xFF, RING, stream);

  cvt(x,   xb,  (size_t)16384 * 1024);
  cvt(W0,  w0b, (size_t)3072 * 1024);
  cvt(Ur0, u0b + 0 * (size_t)1024 * 1024, (size_t)1024 * 1024);
  cvt(Uz0, u0b + 1 * (size_t)1024 * 1024, (size_t)1024 * 1024);
  cvt(Un0, u0b + 2 * (size_t)1024 * 1024, (size_t)1024 * 1024);
  cvt(W1,  w1b, (size_t)3072 * 2048);
  cvt(Ur1, u1b + 0 * (size_t)1024 * 1024, (size_t)1024 * 1024);
  cvt(Uz1, u1b + 1 * (size_t)1024 * 1024, (size_t)1024 * 1024);
  cvt(Un1, u1b + 2 * (size_t)1024 * 1024, (size_t)1024 * 1024);

  // layer 0: xp0 = x @ W0^T + b0  (3072 blocks, XCD-swizzled)
  hipLaunchKernelGGL(gemm_bt_bias, dim3(3072), dim3(256), 0, stream,
                     xb, w0b, b0, xp, 16384, 3072, 1024);
  // layer 0 recurrence -> out0b (bf16), hidden slots 0,1
  hipLaunchKernelGGL(gru_layer, dim3(256), dim3(512), 0, stream,
                     xp, u0b, bn0, hring,
                     out0b, (float*)nullptr,
                     out + (size_t)33554432);
  // re-sentinel the ring for layer 1 (stream-ordered after layer 0)
  hipMemsetAsync(hring, 0xFF, RING, stream);
  // layer 1: xp1 = out0 @ W1^T + b1
  hipLaunchKernelGGL(gemm_bt_bias, dim3(3072), dim3(256), 0, stream,
                     out0b, w1b, b1, xp, 16384, 3072, 2048);
  // layer 1 recurrence -> d_out (f32), hidden slots 2,3
  hipLaunchKernelGGL(gru_layer, dim3(256), dim3(512), 0, stream,
                     xp, u1b, bn1, hring,
                     (uint16_t*)nullptr, out,
                     out + (size_t)33554432 + (size_t)2 * 64 * 1024);
}